// Round 11
// baseline (1422.932 us; speedup 1.0000x reference)
//
#include <hip/hip_runtime.h>
#include <hip/hip_bf16.h>
#include <math.h>

#define VOCAB 32000
#define EMB   256
#define HID   512
#define BB    4
#define SS    512
#define G4H   2048   // 4*HID
#define BS    2048   // BB*SS
#define NLSTM 64
#define NW    500    // worker WGs

typedef unsigned int   u32;
typedef unsigned short u16;
using short8 = __attribute__((ext_vector_type(8))) short;
using f32x4  = __attribute__((ext_vector_type(4))) float;

// workspace layout (float units).
//   xp lives in [0, 4194304) for the whole fused kernel (read by LSTM role).
//   No WB buffer anymore (W converted on the fly by workers).
#define OFF_HSB  8192000ull   // hsaveB: 2048*512 bf16 = 524288 float-slots
#define OFF_HW   8716288ull   // hw: 2*4*512 u32 tagged h words = 4096 slots
#define OFF_PRG  8720384ull   // prog: 64 u32 (inside existing memset range)
#define OFF_SUM  8722432ull   // sumexp: 2048 floats
// end = 8724480 floats = 34.9 MB

__device__ inline unsigned packbf(float a, float b) {
    unsigned ua = __float_as_uint(a), ub = __float_as_uint(b);
    ua += 0x7fffu + ((ua >> 16) & 1u);
    ub += 0x7fffu + ((ub >> 16) & 1u);
    return (ua >> 16) | (ub & 0xffff0000u);
}

__device__ inline float lo16(unsigned w) { return __uint_as_float(w << 16); }
__device__ inline float hi16(unsigned w) { return __uint_as_float(w & 0xffff0000u); }

__device__ inline float fast_tanh(float x) {
    return 1.f - 2.f / (__expf(2.f * x) + 1.f);
}

#define GLOAD_LDS16(gp, lp) __builtin_amdgcn_global_load_lds( \
    (const __attribute__((address_space(1))) void*)(gp),      \
    (__attribute__((address_space(3))) void*)(lp), 16, 0, 0)

// ---------------------------------------------------------------------------
// k1: xp = embeds @ w_ih^T + b_ih + b_hh, in the LSTM WG-local layout:
//   xp2[ ((c*16 + slice)*SS + t)*128 + g*32 + (j&31) ]   (identical to R6)
// ---------------------------------------------------------------------------
__global__ __launch_bounds__(256) void k_embed_xp(
    const int* __restrict__ batch, const float* __restrict__ emb,
    const float* __restrict__ w_ih, const float* __restrict__ b_ih,
    const float* __restrict__ b_hh, float* __restrict__ xp)
{
    __shared__ float Asl[16 * 64];
    __shared__ float Bsl[16 * 64];
    const int tid = threadIdx.x;
    const int bs0 = blockIdx.x * 64;
    const int g0  = blockIdx.y * 64;
    const int m  = tid & 63;
    const int kg = tid >> 6;
    const int tok = batch[bs0 + m];
    const float* arow = emb + (size_t)tok * EMB;
    const float* brow = w_ih + (size_t)(g0 + m) * EMB;
    const int tm = tid >> 4;
    const int tv = tid & 15;

    float acc[4][4] = {};
    for (int k0 = 0; k0 < EMB; k0 += 16) {
        float4 a4 = *(const float4*)(arow + k0 + kg * 4);
        float4 b4 = *(const float4*)(brow + k0 + kg * 4);
        __syncthreads();
        const int kb = kg * 4;
        Asl[(kb + 0) * 64 + m] = a4.x;
        Asl[(kb + 1) * 64 + m] = a4.y;
        Asl[(kb + 2) * 64 + m] = a4.z;
        Asl[(kb + 3) * 64 + m] = a4.w;
        Bsl[(kb + 0) * 64 + m] = b4.x;
        Bsl[(kb + 1) * 64 + m] = b4.y;
        Bsl[(kb + 2) * 64 + m] = b4.z;
        Bsl[(kb + 3) * 64 + m] = b4.w;
        __syncthreads();
#pragma unroll
        for (int k = 0; k < 16; ++k) {
            float4 av = *(const float4*)&Asl[k * 64 + tm * 4];
            float4 bv = *(const float4*)&Bsl[k * 64 + tv * 4];
            float a[4] = {av.x, av.y, av.z, av.w};
            float bb[4] = {bv.x, bv.y, bv.z, bv.w};
#pragma unroll
            for (int i = 0; i < 4; ++i)
#pragma unroll
                for (int j = 0; j < 4; ++j)
                    acc[i][j] += a[i] * bb[j];
        }
    }
    float bsum[4];
#pragma unroll
    for (int j = 0; j < 4; ++j) {
        int g = g0 + tv * 4 + j;
        bsum[j] = b_ih[g] + b_hh[g];
    }
    const int cg = g0 + tv * 4;
    const int gg = cg >> 9;
    const int jj = cg & 511;
    const int sl = jj >> 5;
    const int li = jj & 31;
#pragma unroll
    for (int i = 0; i < 4; ++i) {
        int row = bs0 + tm * 4 + i;
        int cch = row >> 9, tt = row & 511;
        float4 o;
        o.x = acc[i][0] + bsum[0];
        o.y = acc[i][1] + bsum[1];
        o.z = acc[i][2] + bsum[2];
        o.w = acc[i][3] + bsum[3];
        *(float4*)(xp + ((size_t)(cch * 16 + sl) * SS + tt) * 128 +
                   gg * 32 + li) = o;
    }
}

// ---------------------------------------------------------------------------
// k_fused: blocks 0..63   = R6 LSTM (byte-equivalent wire) + release-prog
//          blocks 64..563 = logit-GEMM workers, gated on prog, W converted
//                           fp32->bf16 on the fly. exp/row-sum -> sumexp.
// ---------------------------------------------------------------------------
__global__ __launch_bounds__(512) void k_fused(
    const float* __restrict__ w_hh, const float* __restrict__ xp2,
    u32* __restrict__ hw, u32* __restrict__ prog, u16* __restrict__ hsaveB,
    const float* __restrict__ Wm, const float* __restrict__ bias,
    float* __restrict__ sumexp)
{
    __shared__ u16 As[128 * 64];     // worker A tile (16KB)
    __shared__ u16 Bs[256 * 64];     // worker B tile (32KB)
    __shared__ float hl[4 * 132];    // LSTM h (2.1KB)
    __shared__ float gacc[128];      // LSTM gate sums

    const int bid = blockIdx.x;
    const int tid = threadIdx.x;

    if (bid < NLSTM) {
        // =================== LSTM role (R6 frame, unchanged wire) =========
        const int c     = bid >> 4;        // chain 0..3
        const int slice = bid & 15;
        const int j0    = slice * 32;
        const int r     = tid >> 2;        // gate row in slice 0..127
        const int q     = tid & 3;         // K-quarter
        const int grow  = (r >> 5) * HID + j0 + (r & 31);

        unsigned wreg[64];
        {
            const float* wsrc = w_hh + (size_t)grow * HID + q * 128;
#pragma unroll
            for (int i = 0; i < 32; ++i) {
                float4 f = *(const float4*)(wsrc + i * 4);
                wreg[2 * i]     = packbf(f.x, f.y);
                wreg[2 * i + 1] = packbf(f.z, f.w);
            }
        }

        const float* xbase = xp2 + (size_t)(c * 16 + slice) * (SS * 128) + r;
        float cst = 0.f;

        for (int t = 0; t < SS; ++t) {
            const int p = t & 1;
            float xsv = xbase[t * 128];
            // poll tagged h word (proven R6 wire)
            u32 w;
            {
                u32* addr = hw + p * (BB * HID) + c * HID + tid;
                int guard = 0;
                for (;;) {
                    w = __hip_atomic_load(addr, __ATOMIC_RELAXED,
                                          __HIP_MEMORY_SCOPE_AGENT);
                    if ((w & 0xffffu) == (u32)t) break;
                    __builtin_amdgcn_s_sleep(1);
                    if (++guard > 2000000) break;
                }
            }
            hl[(tid >> 7) * 132 + (tid & 127)] =
                __uint_as_float(w & 0xffff0000u);
            __syncthreads();

            float a0 = 0.f, a1 = 0.f, a2 = 0.f, a3 = 0.f;
            {
                const float4* h4 = (const float4*)&hl[q * 132];
#pragma unroll
                for (int k = 0; k < 32; k += 4) {
                    float4 v0 = h4[k + 0];
                    unsigned wa = wreg[2 * k + 0], wb = wreg[2 * k + 1];
                    a0 = fmaf(v0.x, lo16(wa), a0);
                    a0 = fmaf(v0.y, hi16(wa), a0);
                    a0 = fmaf(v0.z, lo16(wb), a0);
                    a0 = fmaf(v0.w, hi16(wb), a0);
                    float4 v1 = h4[k + 1];
                    wa = wreg[2 * k + 2]; wb = wreg[2 * k + 3];
                    a1 = fmaf(v1.x, lo16(wa), a1);
                    a1 = fmaf(v1.y, hi16(wa), a1);
                    a1 = fmaf(v1.z, lo16(wb), a1);
                    a1 = fmaf(v1.w, hi16(wb), a1);
                    float4 v2 = h4[k + 2];
                    wa = wreg[2 * k + 4]; wb = wreg[2 * k + 5];
                    a2 = fmaf(v2.x, lo16(wa), a2);
                    a2 = fmaf(v2.y, hi16(wa), a2);
                    a2 = fmaf(v2.z, lo16(wb), a2);
                    a2 = fmaf(v2.w, hi16(wb), a2);
                    float4 v3 = h4[k + 3];
                    wa = wreg[2 * k + 6]; wb = wreg[2 * k + 7];
                    a3 = fmaf(v3.x, lo16(wa), a3);
                    a3 = fmaf(v3.y, hi16(wa), a3);
                    a3 = fmaf(v3.z, lo16(wb), a3);
                    a3 = fmaf(v3.w, hi16(wb), a3);
                }
            }
            float acc = (a0 + a1) + (a2 + a3);
            acc += __shfl_xor(acc, 1);
            acc += __shfl_xor(acc, 2);
            if (q == 0) gacc[r] = acc + xsv;
            __syncthreads();

            if (tid < 32) {
                float iv = gacc[tid],      fv = gacc[32 + tid];
                float gv = gacc[64 + tid], ov = gacc[96 + tid];
                float si = 1.f / (1.f + __expf(-iv));
                float sf = 1.f / (1.f + __expf(-fv));
                float so = 1.f / (1.f + __expf(-ov));
                cst = sf * cst + si * fast_tanh(gv);
                float hv = so * fast_tanh(cst);
                unsigned uu = __float_as_uint(hv);
                uu += 0x7fffu + ((uu >> 16) & 1u);
                uu &= 0xffff0000u;
                // wire word first (consumers poll this)
                __hip_atomic_store(
                    hw + (p ^ 1) * (BB * HID) + c * HID + j0 + tid,
                    uu | (u32)(t + 1), __ATOMIC_RELAXED,
                    __HIP_MEMORY_SCOPE_AGENT);
                // archive store: WRITE-THROUGH (sc0 sc1) so cross-XCD
                // first-touch readers get fresh data from the MALL
                const u16* hsp = hsaveB + (size_t)(c * SS + t) * HID + j0 + tid;
                u32 hval = uu >> 16;
                asm volatile("global_store_short %0, %1, off sc0 sc1"
                             :: "v"(hsp), "v"(hval) : "memory");
            }
            // release progress every 128 steps: drain wave-0 stores, publish
            if (((t + 1) & 127) == 0) {
                if (tid < 64)
                    asm volatile("s_waitcnt vmcnt(0)" ::: "memory");
                if (tid == 0)
                    __hip_atomic_store(&prog[c * 16 + slice], (u32)(t + 1),
                                       __ATOMIC_RELAXED,
                                       __HIP_MEMORY_SCOPE_AGENT);
            }
        }
        return;
    }

    // ======================= worker role ==================================
    const int w    = bid - NLSTM;        // 0..NW-1
    const int lane = tid & 63;
    const int wave = tid >> 6;           // 0..7
    const int wr   = wave >> 2;          // bs half 0..1
    const int wc   = wave & 3;           // v quadrant 0..3
    const int lr   = lane & 15;
    const int lc   = lane >> 4;

    for (int r = 0; r < 4; ++r) {
        const u32 target = (u32)((r + 1) * 128);
        for (int j = w; j < 500; j += NW) {
            const int c   = j / 125;
            const int vt  = j - c * 125;
            const int bs0 = c * 512 + r * 128;
            const int v0  = vt * 256;

            // gate: chain c's 16 slices all past step target (hsave rows
            // [bs0, bs0+128) drained to MALL by the vmcnt-release)
            if (tid < 16) {
                int guard = 0;
                for (;;) {
                    u32 pv = __hip_atomic_load(&prog[c * 16 + tid],
                                               __ATOMIC_RELAXED,
                                               __HIP_MEMORY_SCOPE_AGENT);
                    if (pv >= target) break;
                    __builtin_amdgcn_s_sleep(127);
                    __builtin_amdgcn_s_sleep(127);
                    __builtin_amdgcn_s_sleep(127);
                    if (++guard > 300000) break;
                }
            }
            __syncthreads();

            f32x4 acc[4][4];
#pragma unroll
            for (int m = 0; m < 4; ++m)
#pragma unroll
                for (int n = 0; n < 4; ++n)
                    acc[m][n] = (f32x4){0.f, 0.f, 0.f, 0.f};

            for (int k0 = 0; k0 < HID; k0 += 64) {
                // A tile: 128 rows x 64 cols bf16 via global_load_lds,
                // chunk-XOR pre-swizzled source (as k3)
#pragma unroll
                for (int it = 0; it < 2; ++it) {
                    int base = it * 512 + wave * 64;
                    int idx  = base + lane;
                    int row  = idx >> 3, cl = idx & 7;
                    int gcl  = cl ^ (row & 7);
                    const u16* gA = hsaveB + (size_t)(bs0 + row) * HID +
                                    k0 + gcl * 8;
                    GLOAD_LDS16(gA, As + (size_t)base * 8);
                }
                // B tile: 256 rows x 64 cols, fp32 W -> bf16 in registers,
                // ds_write with the same XOR chunk placement
#pragma unroll
                for (int it = 0; it < 4; ++it) {
                    int idx = it * 512 + tid;
                    int row = idx >> 3, l = idx & 7;
                    int g   = l ^ (row & 7);
                    const float* src = Wm + (size_t)(v0 + row) * HID +
                                       k0 + g * 8;
                    float4 f0 = *(const float4*)src;
                    float4 f1 = *(const float4*)(src + 4);
                    uint4 pk;
                    pk.x = packbf(f0.x, f0.y);
                    pk.y = packbf(f0.z, f0.w);
                    pk.z = packbf(f1.x, f1.y);
                    pk.w = packbf(f1.z, f1.w);
                    *(uint4*)&Bs[row * 64 + l * 8] = pk;
                }
                asm volatile("s_waitcnt vmcnt(0)" ::: "memory");
                __syncthreads();

                short8 af[4][2], bf[4][2];
#pragma unroll
                for (int m = 0; m < 4; ++m)
#pragma unroll
                    for (int ks = 0; ks < 2; ++ks) {
                        int rowA = wr * 64 + m * 16 + lr;
                        int swa  = ((ks * 4 + lc) ^ (rowA & 7)) * 8;
                        af[m][ks] = *(const short8*)&As[rowA * 64 + swa];
                        int rowB = wc * 64 + m * 16 + lr;
                        int swb  = ((ks * 4 + lc) ^ (rowB & 7)) * 8;
                        bf[m][ks] = *(const short8*)&Bs[rowB * 64 + swb];
                    }
#pragma unroll
                for (int m = 0; m < 4; ++m)
#pragma unroll
                    for (int n = 0; n < 4; ++n)
#pragma unroll
                        for (int ks = 0; ks < 2; ++ks)
                            acc[m][n] = __builtin_amdgcn_mfma_f32_16x16x32_bf16(
                                af[m][ks], bf[n][ks], acc[m][n], 0, 0, 0);
                __syncthreads();
            }

            float bn[4];
#pragma unroll
            for (int n = 0; n < 4; ++n)
                bn[n] = bias[v0 + wc * 64 + n * 16 + lr];

#pragma unroll
            for (int m = 0; m < 4; ++m) {
                float p0 = 0.f, p1 = 0.f, p2 = 0.f, p3 = 0.f;
#pragma unroll
                for (int n = 0; n < 4; ++n) {
                    float b = bn[n];
                    p0 += __expf(acc[m][n][0] + b);
                    p1 += __expf(acc[m][n][1] + b);
                    p2 += __expf(acc[m][n][2] + b);
                    p3 += __expf(acc[m][n][3] + b);
                }
#pragma unroll
                for (int off = 1; off < 16; off <<= 1) {
                    p0 += __shfl_xor(p0, off);
                    p1 += __shfl_xor(p1, off);
                    p2 += __shfl_xor(p2, off);
                    p3 += __shfl_xor(p3, off);
                }
                if (lr == 0) {
                    int row = bs0 + wr * 64 + m * 16 + lc * 4;
                    atomicAdd(&sumexp[row + 0], p0);
                    atomicAdd(&sumexp[row + 1], p1);
                    atomicAdd(&sumexp[row + 2], p2);
                    atomicAdd(&sumexp[row + 3], p3);
                }
            }
        }
    }
}

// ---------------------------------------------------------------------------
// k4: one wave per (b,s): decode contiguous-view gather, recompute picked
// logit (bf16 h x fp32 W), subtract log(sumexp), accumulate -mean.
// ---------------------------------------------------------------------------
__global__ __launch_bounds__(256) void k_final(
    const int* __restrict__ batch, const u16* __restrict__ hsaveB,
    const float* __restrict__ Wm, const float* __restrict__ bias,
    const float* __restrict__ sumexp, float* __restrict__ out)
{
    const int gt   = blockIdx.x * 256 + threadIdx.x;
    const int wid  = gt >> 6;
    const int lane = gt & 63;
    const unsigned tgt = (unsigned)batch[wid];
    const unsigned s2 = wid >> 2, b2 = wid & 3;
    const unsigned j = s2 * (VOCAB * BB) + tgt * BB + b2;
    const unsigned SV = (unsigned)SS * VOCAB;
    const unsigned b_o = j / SV;
    const unsigned rr = j - b_o * SV;
    const unsigned s_o = rr / VOCAB;
    const unsigned v_o = rr - s_o * VOCAB;
    const unsigned row = b_o * SS + s_o;

    uint4 hu = *(const uint4*)(hsaveB + (size_t)row * HID + lane * 8);
    const float* wp = Wm + (size_t)v_o * HID + lane * 8;
    float4 w0 = *(const float4*)wp;
    float4 w1 = *(const float4*)(wp + 4);
    float d = lo16(hu.x) * w0.x + hi16(hu.x) * w0.y +
              lo16(hu.y) * w0.z + hi16(hu.y) * w0.w +
              lo16(hu.z) * w1.x + hi16(hu.z) * w1.y +
              lo16(hu.w) * w1.z + hi16(hu.w) * w1.w;
#pragma unroll
    for (int off = 32; off >= 1; off >>= 1)
        d += __shfl_xor(d, off);
    if (lane == 0) {
        float picked = d + bias[v_o] - logf(sumexp[row]);
        atomicAdd(out, -picked * (1.f / (float)BS));
    }
}

// ---------------------------------------------------------------------------
extern "C" void kernel_launch(void* const* d_in, const int* in_sizes, int n_in,
                              void* d_out, int out_size, void* d_ws, size_t ws_size,
                              hipStream_t stream)
{
    const int*   batch = (const int*)d_in[0];
    const float* emb   = (const float*)d_in[1];
    const float* w_ih  = (const float*)d_in[2];
    const float* w_hh  = (const float*)d_in[3];
    const float* b_ih  = (const float*)d_in[4];
    const float* b_hh  = (const float*)d_in[5];
    const float* Wm    = (const float*)d_in[6];
    const float* bvec  = (const float*)d_in[7];
    float* out = (float*)d_out;
    float* ws  = (float*)d_ws;

    float* xp      = ws;
    u16*   hsaveB  = (u16*)(ws + OFF_HSB);
    u32*   hw      = (u32*)(ws + OFF_HW);
    u32*   prog    = (u32*)(ws + OFF_PRG);
    float* sumexp  = ws + OFF_SUM;

    // zero hw + prog + sumexp (contiguous) and out
    hipMemsetAsync(hw, 0, (4096 + 2048 + 2048) * sizeof(float), stream);
    hipMemsetAsync(out, 0, sizeof(float), stream);

    dim3 g1(BS / 64, G4H / 64);
    k_embed_xp<<<g1, 256, 0, stream>>>(batch, emb, w_ih, b_ih, b_hh, xp);

    k_fused<<<NLSTM + NW, 512, 0, stream>>>(w_hh, xp, hw, prog, hsaveB,
                                            Wm, bvec, sumexp);

    k_final<<<BS * 64 / 256, 256, 0, stream>>>(batch, hsaveB, Wm, bvec,
                                               sumexp, out);
}